// Round 6
// baseline (293.910 us; speedup 1.0000x reference)
//
#include <hip/hip_runtime.h>

#define LOG2PI 1.8378770664093453

__device__ __forceinline__ float rl32(float v, int l) {
  return __int_as_float(__builtin_amdgcn_readlane(__float_as_int(v), l));
}

// One 64-thread wave processes instance pair (2i, 2i+1) SEQUENTIALLY.
// Why: Next_coefs lines (128B) span {inst 2i, 2i+1} x k for fixed j. Any
// scheme that emits 64B partial-line stores scattered in time pays full-line
// writeback + read-for-ownership per store (r3/r4/r5 all measured WRITE
// ~304MB = 16 j-steps x 8192 insts x 128B, vs 9MB of output). Stashing both
// insts' R in LDS and writing full 128B lines from single wave instructions
// eliminates both. Single-wave blocks: barriers elided (r5's 2-wave blocks
// regressed 155->213us from barrier coupling).
// Phase 1 (QR on A + projection): sign-free -> Gram + Cholesky + solves (f32).
// Phase 2 (QR on PB; LAPACK signs matter): compressed Householder recursion
// on (Gram(PB,Pc) 17x17, top-16 rows of [PB|Pc]); beta = -sign(alpha)*norm.
__global__ __launch_bounds__(64, 3) void cint_kernel(
    const float* __restrict__ input_i,
    const float* __restrict__ Prev_coefs,
    const float* __restrict__ Prev_biases,
    const float* __restrict__ LPin,
    const float* __restrict__ Log_factors,
    const float* __restrict__ obs_var,
    const float* __restrict__ hid_var,
    const float* __restrict__ nxt_var,
    const float* __restrict__ rec_biases,
    float* __restrict__ out,
    int NBP)
{
  __shared__ float X[64*36];    // [A(16)|B(16)|c(1)|pad] f32, row stride 36
  __shared__ float S[16*34];    // rows: S_AA(16)|S_AB(16)|S_Ac|stash 1/Ljj
  __shared__ float W[16*20];    // W (16 cols) + w (col 16), stride 20
  __shared__ float M2[2];       // [0]=||Pc||^2, [1]=LC1
  __shared__ float Rst[2*16*20];// R rows stash: [il][j][k], stride 20 (16B ok)
  __shared__ float Bst[32];     // Next_biases stash [il][j]
  __shared__ float LPst[2];     // LP stash

  const int lane = threadIdx.x;
  // XCD-chunked bijective swizzle over 4096 pair-blocks.
  const int bid   = blockIdx.x;
  const int npair = NBP >> 1;
  const int base  = ((bid & 7) * (npair >> 3) + (bid >> 3)) * 2;

  float* PB = X;   // reused after P3: [64][20] f32, cols 0..15 PB, 16 Pc
  float* G  = S;   // reused after P2: [16][18] f32 Gram of [PB|Pc]

  const size_t NB_OFFv = (size_t)NBP * 256;  // 16*NBP*16
  const size_t LP_OFFv = NB_OFFv + (size_t)NBP * 16;

  #pragma unroll 1
  for (int h = 0; h < 2; ++h) {
    const int inst = base + h;
    const float lp_lf = LPin[inst] + Log_factors[inst];

    // ---------------- P0: stage X = [A | B | c] ----------------
    {
      const int g  = lane;
      const int gh = g - 16;
      const size_t rowidx = (g < 16) ? ((size_t)g * NBP + inst)
                                     : ((size_t)gh * NBP + inst);
      const float* aptr = (g < 16) ? (Prev_coefs + rowidx * 16)
                                   : (hid_var    + rowidx * 16);
      float4 a0 = *(const float4*)(aptr + 0);
      float4 a1 = *(const float4*)(aptr + 4);
      float4 a2 = *(const float4*)(aptr + 8);
      float4 a3 = *(const float4*)(aptr + 12);
      *(float4*)&X[g*36 +  0] = a0;
      *(float4*)&X[g*36 +  4] = a1;
      *(float4*)&X[g*36 +  8] = a2;
      *(float4*)&X[g*36 + 12] = a3;
      float4 z4 = make_float4(0.f, 0.f, 0.f, 0.f);
      float4 b0 = z4, b1 = z4, b2 = z4, b3 = z4;
      float cv;
      if (g < 16) {
        cv = Prev_biases[rowidx];
      } else {
        const float* bptr = nxt_var + rowidx * 16;
        b0 = *(const float4*)(bptr + 0);
        b1 = *(const float4*)(bptr + 4);
        b2 = *(const float4*)(bptr + 8);
        b3 = *(const float4*)(bptr + 12);
        float4 ob = *(const float4*)(obs_var + rowidx * 4);
        float4 iv = *(const float4*)(input_i + (size_t)inst * 4);
        cv = rec_biases[rowidx] + ob.x*iv.x + ob.y*iv.y + ob.z*iv.z + ob.w*iv.w;
      }
      *(float4*)&X[g*36 + 16] = b0;
      *(float4*)&X[g*36 + 20] = b1;
      *(float4*)&X[g*36 + 24] = b2;
      *(float4*)&X[g*36 + 28] = b3;
      X[g*36 + 32] = cv;
    }
    __syncthreads();

    // ---------------- P1: S[i][k] = sum_g A[g,i]*X[g,k], i<16, k<33 --------
    {
      const int i  = lane & 15;
      const int kq = lane >> 4;     // cols 8kq..8kq+7 (+ col 32 for kq==0)
      float ac0=0, ac1=0, ac2=0, ac3=0, ac4=0, ac5=0, ac6=0, ac7=0, ac8=0;
      #pragma unroll 8
      for (int g = 0; g < 64; ++g) {
        const float* xr = &X[g*36];
        float  xi = xr[i];
        float4 c0 = *(const float4*)(xr + 8*kq);
        float4 c1 = *(const float4*)(xr + 8*kq + 4);
        float  cc = xr[32];
        ac0 = fmaf(xi, c0.x, ac0);
        ac1 = fmaf(xi, c0.y, ac1);
        ac2 = fmaf(xi, c0.z, ac2);
        ac3 = fmaf(xi, c0.w, ac3);
        ac4 = fmaf(xi, c1.x, ac4);
        ac5 = fmaf(xi, c1.y, ac5);
        ac6 = fmaf(xi, c1.z, ac6);
        ac7 = fmaf(xi, c1.w, ac7);
        ac8 = fmaf(xi, cc,  ac8);
      }
      float* srow = &S[i*34 + 8*kq];
      srow[0]=ac0; srow[1]=ac1; srow[2]=ac2; srow[3]=ac3;
      srow[4]=ac4; srow[5]=ac5; srow[6]=ac6; srow[7]=ac7;
      if (kq == 0) S[i*34 + 32] = ac8;
    }
    __syncthreads();

    // ---------------- P2a: Cholesky of S_AA (rows in registers) -----------
    float Lr[16];
    {
      const int ir = lane & 15;
      double prodd = 1.0;
      #pragma unroll
      for (int j = 0; j < 16; ++j) {
        float s = S[ir*34 + j];
        #pragma unroll
        for (int m = 0; m < j; ++m) s = fmaf(-Lr[m], rl32(Lr[m], j), s);
        float sj = rl32(s, j);
        sj = fmaxf(sj, 1e-30f);
        float Ljj = sqrtf(sj);
        float iv  = 1.0f / Ljj;
        prodd *= (double)sj;
        Lr[j] = (ir == j) ? Ljj : s * iv;
        if (lane == j) S[j*34 + 33] = iv;   // stash 1/L_jj
      }
      if (lane == 0) M2[1] = (float)(-0.5 * log(prodd));  // LC1
    }

    // ---------------- P2b: solve S_AA * [W|w] = [S_AB|S_Ac] (17 RHS) ------
    {
      const int rc = (lane < 17) ? lane : 16;
      float x[16];
      #pragma unroll
      for (int j = 0; j < 16; ++j) {
        float t = S[j*34 + 16 + rc];
        #pragma unroll
        for (int m = 0; m < j; ++m) t = fmaf(-rl32(Lr[m], j), x[m], t);
        x[j] = t * S[j*34 + 33];
      }
      #pragma unroll
      for (int j = 15; j >= 0; --j) {
        float t = x[j];
        #pragma unroll
        for (int m = j + 1; m < 16; ++m) t = fmaf(-rl32(Lr[j], m), x[m], t);
        x[j] = t * S[j*34 + 33];
      }
      if (lane < 17) {
        #pragma unroll
        for (int m = 0; m < 16; ++m) W[m*20 + lane] = x[m];
      }
    }
    __syncthreads();

    // ---------------- P3: PB = B - A*W, Pc = c - A*w; ||Pc||^2 ------------
    {
      const int g = lane;
      const float* xr = &X[g*36];
      float4 a0 = *(const float4*)(xr + 0);
      float4 a1 = *(const float4*)(xr + 4);
      float4 a2 = *(const float4*)(xr + 8);
      float4 a3 = *(const float4*)(xr + 12);
      float ad[16] = { a0.x,a0.y,a0.z,a0.w, a1.x,a1.y,a1.z,a1.w,
                       a2.x,a2.y,a2.z,a2.w, a3.x,a3.y,a3.z,a3.w };
      float4 e0 = *(const float4*)(xr + 16);
      float4 e1 = *(const float4*)(xr + 20);
      float4 e2 = *(const float4*)(xr + 24);
      float4 e3 = *(const float4*)(xr + 28);
      float pb[17] = { e0.x,e0.y,e0.z,e0.w, e1.x,e1.y,e1.z,e1.w,
                       e2.x,e2.y,e2.z,e2.w, e3.x,e3.y,e3.z,e3.w, xr[32] };
      #pragma unroll
      for (int m = 0; m < 16; ++m) {
        const float* wr = &W[m*20];
        float am = ad[m];
        float4 w0 = *(const float4*)(wr + 0);
        float4 w1 = *(const float4*)(wr + 4);
        float4 w2 = *(const float4*)(wr + 8);
        float4 w3 = *(const float4*)(wr + 12);
        pb[0]  = fmaf(-am, w0.x, pb[0]);  pb[1]  = fmaf(-am, w0.y, pb[1]);
        pb[2]  = fmaf(-am, w0.z, pb[2]);  pb[3]  = fmaf(-am, w0.w, pb[3]);
        pb[4]  = fmaf(-am, w1.x, pb[4]);  pb[5]  = fmaf(-am, w1.y, pb[5]);
        pb[6]  = fmaf(-am, w1.z, pb[6]);  pb[7]  = fmaf(-am, w1.w, pb[7]);
        pb[8]  = fmaf(-am, w2.x, pb[8]);  pb[9]  = fmaf(-am, w2.y, pb[9]);
        pb[10] = fmaf(-am, w2.z, pb[10]); pb[11] = fmaf(-am, w2.w, pb[11]);
        pb[12] = fmaf(-am, w3.x, pb[12]); pb[13] = fmaf(-am, w3.y, pb[13]);
        pb[14] = fmaf(-am, w3.z, pb[14]); pb[15] = fmaf(-am, w3.w, pb[15]);
        pb[16] = fmaf(-am, wr[16], pb[16]);
      }
      float q = pb[16] * pb[16];
      #pragma unroll
      for (int msk = 1; msk < 64; msk <<= 1) q += __shfl_xor(q, msk, 64);
      if (lane == 0) M2[0] = q;             // ||Pc||^2
      __syncthreads();                      // all X reads done before overwrite
      float4 o0 = { pb[0],  pb[1],  pb[2],  pb[3]  };
      float4 o1 = { pb[4],  pb[5],  pb[6],  pb[7]  };
      float4 o2 = { pb[8],  pb[9],  pb[10], pb[11] };
      float4 o3 = { pb[12], pb[13], pb[14], pb[15] };
      *(float4*)&PB[g*20 +  0] = o0;
      *(float4*)&PB[g*20 +  4] = o1;
      *(float4*)&PB[g*20 +  8] = o2;
      *(float4*)&PB[g*20 + 12] = o3;
      PB[g*20 + 16] = pb[16];
    }
    __syncthreads();

    // ---------------- P4: Ghat[k1][k2] = sum_g PB[g,k1]*PB[g,k2] ----------
    {
      const int k1 = lane & 15;
      const int kq = lane >> 4;    // cols 4kq..4kq+3 (+ col 16 for kq==0)
      float ac0=0, ac1=0, ac2=0, ac3=0, ac4=0;
      #pragma unroll 8
      for (int g = 0; g < 64; ++g) {
        const float* pr = &PB[g*20];
        float  xr = pr[k1];
        float4 cv = *(const float4*)(pr + 4*kq);
        float  cc = pr[16];
        ac0 = fmaf(xr, cv.x, ac0);
        ac1 = fmaf(xr, cv.y, ac1);
        ac2 = fmaf(xr, cv.z, ac2);
        ac3 = fmaf(xr, cv.w, ac3);
        ac4 = fmaf(xr, cc,  ac4);
      }
      float* gr = &G[k1*18 + 4*kq];
      gr[0]=ac0; gr[1]=ac1; gr[2]=ac2; gr[3]=ac3;
      if (kq == 0) G[k1*18 + 16] = ac4;
    }
    __syncthreads();

    // ---------------- P5: compressed Householder QR2 (LAPACK signs) -------
    {
      const int k  = lane;
      const int kc = (k < 17) ? k : 16;   // lane k owns column k (16 = Pc)
      float Tr[16];                        // top-16 rows of my column
      float Gh[16];                        // Ghat[j][k], j<16
      #pragma unroll
      for (int r = 0; r < 16; ++r) Tr[r] = PB[r*20 + kc];
      #pragma unroll
      for (int j = 0; j < 16; ++j) Gh[j] = G[j*18 + kc];
      float nbacc = 0.0f;
      #pragma unroll
      for (int j = 0; j < 16; ++j) {
        float alf  = rl32(Tr[j], j);           // alpha = T[j][j]
        float nrm2 = rl32(Gh[j], j);           // ||active col j||^2
        float nrm  = sqrtf(fmaxf(nrm2, 1e-30f));
        float aa   = fabsf(alf);
        float tau  = 1.0f + aa / nrm;          // (beta-alpha)/beta
        float inv  = copysignf(1.0f / (aa + nrm), alf);  // 1/(alpha-beta)
        float beta = -copysignf(nrm, alf);     // LAPACK R_jj
        float Tj   = Tr[j];
        float wv   = Tj + (Gh[j] - alf * Tj) * inv;      // v^T col_k
        float Rv   = Tj - tau * wv;                      // R[j][k], k>=j
        if (k < 16) {                          // stash R row j (LDS, not HBM)
          float ov = (k < j) ? 0.0f : ((k == j) ? beta : Rv);
          Rst[(h*16 + j)*20 + k] = ov;
        } else if (k == 16) {
          Bst[h*16 + j] = Rv;
          nbacc = fmaf(Rv, Rv, nbacc);
        }
        float twi = tau * wv * inv;
        #pragma unroll
        for (int r = j + 1; r < 16; ++r) {     // T update (rows > j)
          float vr = rl32(Tr[r], j);           // v_r*(alpha-beta) = T[r][j]
          Tr[r] = fmaf(-twi, vr, Tr[r]);
        }
        #pragma unroll
        for (int l = j + 1; l < 16; ++l) {     // Ghat -= R_j outer R_j
          float Rl = rl32(Rv, l);
          Gh[l] = fmaf(-Rl, Rv, Gh[l]);
        }
      }
      if (k == 16) {
        double resid = fmax((double)M2[0] - (double)nbacc, 0.0);
        double LC = (double)M2[1] - 0.5 * (32.0 * LOG2PI + resid);
        LPst[h] = lp_lf + (float)LC;
      }
    }
    __syncthreads();
  }

  // ---------------- Epilogue: full-128B-line coalesced stores --------------
  // Next_coefs: line (j fixed) = {inst base, base+1} x k(0..15) = 128B.
  // Each pass: one wave store instruction covers 8 complete lines.
  #pragma unroll
  for (int p = 0; p < 2; ++p) {
    const int t  = p * 64 + lane;
    const int j  = t >> 3;
    const int r  = t & 7;
    const int il = r >> 2;
    const int kq = r & 3;
    float4 v = *(const float4*)&Rst[(il*16 + j)*20 + kq*4];
    *(float4*)&out[((size_t)j * NBP + base + il) * 16 + kq*4] = v;
  }
  if (lane < 32) {
    const int j  = lane >> 1;
    const int il = lane & 1;
    out[NB_OFFv + (size_t)j * NBP + base + il] = Bst[il*16 + j];
  }
  if (lane < 2) out[LP_OFFv + base + lane] = LPst[lane];
}

extern "C" void kernel_launch(void* const* d_in, const int* in_sizes, int n_in,
                              void* d_out, int out_size, void* d_ws, size_t ws_size,
                              hipStream_t stream) {
  (void)n_in; (void)out_size; (void)d_ws; (void)ws_size;
  const int NBP = in_sizes[3];              // B*P (LP element count) = 8192
  cint_kernel<<<NBP / 2, 64, 0, stream>>>(
      (const float*)d_in[0], (const float*)d_in[1], (const float*)d_in[2],
      (const float*)d_in[3], (const float*)d_in[4], (const float*)d_in[5],
      (const float*)d_in[6], (const float*)d_in[7], (const float*)d_in[8],
      (float*)d_out, NBP);
}

// Round 7
// 182.096 us; speedup vs baseline: 1.6140x; 1.6140x over previous
//
#include <hip/hip_runtime.h>

#define LOG2PI 1.8378770664093453

__device__ __forceinline__ float rl32(float v, int l) {
  return __int_as_float(__builtin_amdgcn_readlane(__float_as_int(v), l));
}

// One (b,p) instance per 128-thread block, TWO COOPERATIVE waves.
// r4 (1 wave/inst, 12 waves/CU) was latency-bound: VALUBusy 35%, Occ 27%.
// Split the throughput phases (P1/P4 Gram g-loops: g-range halves + LDS
// merge; P3: column split) across 2 waves and let wave1 idle at barriers
// during the serial phases (P2 Cholesky/solve, P5 Householder, wave0 only).
// 13.9KB LDS -> 11 blocks x 2 waves = 22 waves/CU (vs 12), ~2x latency hiding.
// r5's 2-wave failure was INDEPENDENT insts coupled by barriers; here the
// barriers do productive work-sharing.
// Phase 1 (QR on A + projection): sign-free -> Gram + Cholesky + solves (f32).
// Phase 2 (QR on PB; LAPACK signs matter): compressed Householder recursion
// on (Gram(PB,Pc) 17x17, top-16 rows of [PB|Pc]); beta = -sign(alpha)*norm.
__global__ __launch_bounds__(128, 5) void cint_kernel(
    const float* __restrict__ input_i,
    const float* __restrict__ Prev_coefs,
    const float* __restrict__ Prev_biases,
    const float* __restrict__ LPin,
    const float* __restrict__ Log_factors,
    const float* __restrict__ obs_var,
    const float* __restrict__ hid_var,
    const float* __restrict__ nxt_var,
    const float* __restrict__ rec_biases,
    float* __restrict__ out,
    int NBP)
{
  __shared__ float X[64*36];     // [A(16)|B(16)|c(1)|pad] rows, stride 36
  __shared__ float SD[2][16*36]; // P1 partials; SD[0]=merged S (cols16..=W,
                                 // col33=1/Ljj stash); SD[1] reused as G
  __shared__ float M2[2];        // [0]=||Pc||^2, [1]=LC1

  const int tid  = threadIdx.x;
  const int w    = tid >> 6;
  const int lane = tid & 63;
  const int bid  = blockIdx.x;
  const int inst = (bid & 7) * (NBP >> 3) + (bid >> 3);  // XCD-chunked swizzle

  float* PB  = X;          // after P3: [64][20], cols 0..15 PB, 16 Pc
  float* G   = SD[1];      // after P4 merge: [16][18] Gram of [PB|Pc]
  float* Gp1 = &X[1344];   // wave1's P4 partial (X tail, dead region)

  const size_t NB_OFFv = (size_t)NBP * 256;
  const size_t LP_OFFv = NB_OFFv + (size_t)NBP * 16;

  const float lp_lf = LPin[inst] + Log_factors[inst];

  // ---------------- P0: stage X = [A | B | c]; w0->A, w1->B/c --------------
  {
    const int g = lane;
    const size_t rowidx = (g < 16) ? ((size_t)g * NBP + inst)
                                   : ((size_t)(g - 16) * NBP + inst);
    if (w == 0) {
      const float* aptr = (g < 16) ? (Prev_coefs + rowidx * 16)
                                   : (hid_var    + rowidx * 16);
      *(float4*)&X[g*36 +  0] = *(const float4*)(aptr + 0);
      *(float4*)&X[g*36 +  4] = *(const float4*)(aptr + 4);
      *(float4*)&X[g*36 +  8] = *(const float4*)(aptr + 8);
      *(float4*)&X[g*36 + 12] = *(const float4*)(aptr + 12);
    } else {
      float4 z4 = make_float4(0.f, 0.f, 0.f, 0.f);
      float4 b0 = z4, b1 = z4, b2 = z4, b3 = z4;
      float cv;
      if (g < 16) {
        cv = Prev_biases[rowidx];
      } else {
        const float* bptr = nxt_var + rowidx * 16;
        b0 = *(const float4*)(bptr + 0);
        b1 = *(const float4*)(bptr + 4);
        b2 = *(const float4*)(bptr + 8);
        b3 = *(const float4*)(bptr + 12);
        float4 ob = *(const float4*)(obs_var + rowidx * 4);
        float4 iv = *(const float4*)(input_i + (size_t)inst * 4);
        cv = rec_biases[rowidx] + ob.x*iv.x + ob.y*iv.y + ob.z*iv.z + ob.w*iv.w;
      }
      *(float4*)&X[g*36 + 16] = b0;
      *(float4*)&X[g*36 + 20] = b1;
      *(float4*)&X[g*36 + 24] = b2;
      *(float4*)&X[g*36 + 28] = b3;
      X[g*36 + 32] = cv;
    }
  }
  __syncthreads();

  // ------- P1 partial: Sp_w[i][k] = sum_{g in wave range} A[g,i]X[g,k] -----
  {
    const int i  = lane & 15;
    const int kq = lane >> 4;     // cols 8kq..8kq+7 (+ col 32 for kq==0)
    float ac0=0, ac1=0, ac2=0, ac3=0, ac4=0, ac5=0, ac6=0, ac7=0, ac8=0;
    const int g0 = 32 * w;
    #pragma unroll 8
    for (int g = g0; g < g0 + 32; ++g) {
      const float* xr = &X[g*36];
      float  xi = xr[i];
      float4 c0 = *(const float4*)(xr + 8*kq);
      float4 c1 = *(const float4*)(xr + 8*kq + 4);
      float  cc = xr[32];
      ac0 = fmaf(xi, c0.x, ac0);
      ac1 = fmaf(xi, c0.y, ac1);
      ac2 = fmaf(xi, c0.z, ac2);
      ac3 = fmaf(xi, c0.w, ac3);
      ac4 = fmaf(xi, c1.x, ac4);
      ac5 = fmaf(xi, c1.y, ac5);
      ac6 = fmaf(xi, c1.z, ac6);
      ac7 = fmaf(xi, c1.w, ac7);
      ac8 = fmaf(xi, cc,  ac8);
    }
    float* srow = &SD[w][i*36 + 8*kq];
    srow[0]=ac0; srow[1]=ac1; srow[2]=ac2; srow[3]=ac3;
    srow[4]=ac4; srow[5]=ac5; srow[6]=ac6; srow[7]=ac7;
    if (kq == 0) SD[w][i*36 + 32] = ac8;
  }
  __syncthreads();

  // ------- P1 merge: S = Sp0 + Sp1 into SD[0] (128 thr x 4 cols) -----------
  {
    const int i = tid & 15;
    const int q = tid >> 4;       // 0..7 -> cols 4q..4q+3
    float4 a = *(const float4*)&SD[0][i*36 + 4*q];
    float4 b = *(const float4*)&SD[1][i*36 + 4*q];
    a.x += b.x; a.y += b.y; a.z += b.z; a.w += b.w;
    *(float4*)&SD[0][i*36 + 4*q] = a;
    if (q == 0) SD[0][i*36 + 32] += SD[1][i*36 + 32];
  }
  __syncthreads();

  // ---------------- P2 (wave0 only): Cholesky + 17-RHS solve ---------------
  if (w == 0) {
    float* S = SD[0];
    float Lr[16];
    {
      const int ir = lane & 15;
      double prodd = 1.0;
      #pragma unroll
      for (int j = 0; j < 16; ++j) {
        float s = S[ir*36 + j];
        #pragma unroll
        for (int m = 0; m < j; ++m) s = fmaf(-Lr[m], rl32(Lr[m], j), s);
        float sj = rl32(s, j);
        sj = fmaxf(sj, 1e-30f);
        float Ljj = sqrtf(sj);
        float iv  = 1.0f / Ljj;
        prodd *= (double)sj;
        Lr[j] = (ir == j) ? Ljj : s * iv;
        if (lane == j) S[j*36 + 33] = iv;   // stash 1/L_jj
      }
      if (lane == 0) M2[1] = (float)(-0.5 * log(prodd));  // LC1
    }
    {
      const int rc = (lane < 17) ? lane : 16;
      float x[16];
      #pragma unroll
      for (int j = 0; j < 16; ++j) {
        float t = S[j*36 + 16 + rc];
        #pragma unroll
        for (int m = 0; m < j; ++m) t = fmaf(-rl32(Lr[m], j), x[m], t);
        x[j] = t * S[j*36 + 33];
      }
      #pragma unroll
      for (int j = 15; j >= 0; --j) {
        float t = x[j];
        #pragma unroll
        for (int m = j + 1; m < 16; ++m) t = fmaf(-rl32(Lr[j], m), x[m], t);
        x[j] = t * S[j*36 + 33];
      }
      if (lane < 17) {                       // W overwrites S_AB/S_Ac region
        #pragma unroll
        for (int m = 0; m < 16; ++m) S[m*36 + 16 + lane] = x[m];
      }
    }
  }
  __syncthreads();

  // ---------------- P3: PB = B - A*W (column-split), Pc, ||Pc||^2 ----------
  {
    const int g = lane;
    const float* xr = &X[g*36];
    float4 a0 = *(const float4*)(xr + 0);
    float4 a1 = *(const float4*)(xr + 4);
    float4 a2 = *(const float4*)(xr + 8);
    float4 a3 = *(const float4*)(xr + 12);
    float ad[16] = { a0.x,a0.y,a0.z,a0.w, a1.x,a1.y,a1.z,a1.w,
                     a2.x,a2.y,a2.z,a2.w, a3.x,a3.y,a3.z,a3.w };
    // wave0 owns logical cols 0..7, wave1 owns 8..16 (incl Pc)
    float4 e0, e1; float pc = 0.0f;
    if (w == 0) {
      e0 = *(const float4*)(xr + 16);
      e1 = *(const float4*)(xr + 20);
    } else {
      e0 = *(const float4*)(xr + 24);
      e1 = *(const float4*)(xr + 28);
      pc = xr[32];
    }
    float pb[8] = { e0.x,e0.y,e0.z,e0.w, e1.x,e1.y,e1.z,e1.w };
    __syncthreads();                 // ALL X reads done before PB overwrites
    const float* S0 = SD[0];
    const int coff = 16 + 8*w;       // W col base for this wave
    #pragma unroll
    for (int m = 0; m < 16; ++m) {
      float am = ad[m];
      float4 w0v = *(const float4*)(S0 + m*36 + coff);
      float4 w1v = *(const float4*)(S0 + m*36 + coff + 4);
      pb[0] = fmaf(-am, w0v.x, pb[0]); pb[1] = fmaf(-am, w0v.y, pb[1]);
      pb[2] = fmaf(-am, w0v.z, pb[2]); pb[3] = fmaf(-am, w0v.w, pb[3]);
      pb[4] = fmaf(-am, w1v.x, pb[4]); pb[5] = fmaf(-am, w1v.y, pb[5]);
      pb[6] = fmaf(-am, w1v.z, pb[6]); pb[7] = fmaf(-am, w1v.w, pb[7]);
      if (w == 1) pc = fmaf(-am, S0[m*36 + 32], pc);
    }
    if (w == 1) {                    // ||Pc||^2 reduce within wave1
      float q = pc * pc;
      #pragma unroll
      for (int msk = 1; msk < 64; msk <<= 1) q += __shfl_xor(q, msk, 64);
      if (lane == 0) M2[0] = q;
    }
    float4 o0 = { pb[0], pb[1], pb[2], pb[3] };
    float4 o1 = { pb[4], pb[5], pb[6], pb[7] };
    *(float4*)&PB[g*20 + 8*w + 0] = o0;
    *(float4*)&PB[g*20 + 8*w + 4] = o1;
    if (w == 1) PB[g*20 + 16] = pc;
  }
  __syncthreads();

  // ------- P4 partial: Gp_w[k1][k2] = sum_{g in range} PB[g,k1]PB[g,k2] ----
  {
    float* Gp = (w == 0) ? SD[1] : Gp1;
    const int k1 = lane & 15;
    const int kq = lane >> 4;     // cols 4kq..4kq+3 (+ col 16 for kq==0)
    float ac0=0, ac1=0, ac2=0, ac3=0, ac4=0;
    const int g0 = 32 * w;
    #pragma unroll 8
    for (int g = g0; g < g0 + 32; ++g) {
      const float* pr = &PB[g*20];
      float  xr = pr[k1];
      float4 cv = *(const float4*)(pr + 4*kq);
      float  cc = pr[16];
      ac0 = fmaf(xr, cv.x, ac0);
      ac1 = fmaf(xr, cv.y, ac1);
      ac2 = fmaf(xr, cv.z, ac2);
      ac3 = fmaf(xr, cv.w, ac3);
      ac4 = fmaf(xr, cc,  ac4);
    }
    float* gr = &Gp[k1*18 + 4*kq];
    gr[0]=ac0; gr[1]=ac1; gr[2]=ac2; gr[3]=ac3;
    if (kq == 0) Gp[k1*18 + 16] = ac4;
  }
  __syncthreads();

  // ------- P4 merge: G = Gp0 + Gp1 (into SD[1], own-entry writes) ----------
  {
    const int k1 = tid & 15;
    const int q  = tid >> 4;      // 0..7 -> cols 2q, 2q+1
    G[k1*18 + 2*q]     += Gp1[k1*18 + 2*q];
    G[k1*18 + 2*q + 1] += Gp1[k1*18 + 2*q + 1];
    if (q == 0) G[k1*18 + 16] += Gp1[k1*18 + 16];
  }
  __syncthreads();

  // ---------------- P5 (wave0 only): compressed Householder QR2 ------------
  if (w == 0) {
    const int k  = lane;
    const int kc = (k < 17) ? k : 16;   // lane k owns column k (16 = Pc)
    float Tr[16];
    float Gh[16];
    #pragma unroll
    for (int r = 0; r < 16; ++r) Tr[r] = PB[r*20 + kc];
    #pragma unroll
    for (int j = 0; j < 16; ++j) Gh[j] = G[j*18 + kc];
    float nbacc = 0.0f;
    #pragma unroll
    for (int j = 0; j < 16; ++j) {
      float alf  = rl32(Tr[j], j);           // alpha = T[j][j]
      float nrm2 = rl32(Gh[j], j);           // ||active col j||^2
      float nrm  = sqrtf(fmaxf(nrm2, 1e-30f));
      float aa   = fabsf(alf);
      float tau  = 1.0f + aa / nrm;          // (beta-alpha)/beta
      float inv  = copysignf(1.0f / (aa + nrm), alf);  // 1/(alpha-beta)
      float beta = -copysignf(nrm, alf);     // LAPACK R_jj
      float Tj   = Tr[j];
      float wv   = Tj + (Gh[j] - alf * Tj) * inv;      // v^T col_k
      float Rv   = Tj - tau * wv;                      // R[j][k], k>=j
      if (k < 16) {
        float ov = (k < j) ? 0.0f : ((k == j) ? beta : Rv);
        out[((size_t)j * NBP + inst) * 16 + k] = ov;   // Next_coefs
      } else if (k == 16) {
        out[NB_OFFv + (size_t)j * NBP + inst] = Rv;    // Next_biases
        nbacc = fmaf(Rv, Rv, nbacc);
      }
      float twi = tau * wv * inv;
      #pragma unroll
      for (int r = j + 1; r < 16; ++r) {     // T update (rows > j)
        float vr = rl32(Tr[r], j);
        Tr[r] = fmaf(-twi, vr, Tr[r]);
      }
      #pragma unroll
      for (int l = j + 1; l < 16; ++l) {     // Ghat -= R_j outer R_j
        float Rl = rl32(Rv, l);
        Gh[l] = fmaf(-Rl, Rv, Gh[l]);
      }
    }
    if (k == 16) {
      double resid = fmax((double)M2[0] - (double)nbacc, 0.0);
      double LC = (double)M2[1] - 0.5 * (32.0 * LOG2PI + resid);
      out[LP_OFFv + (size_t)inst] = lp_lf + (float)LC;
    }
  }
}

extern "C" void kernel_launch(void* const* d_in, const int* in_sizes, int n_in,
                              void* d_out, int out_size, void* d_ws, size_t ws_size,
                              hipStream_t stream) {
  (void)n_in; (void)out_size; (void)d_ws; (void)ws_size;
  const int NBP = in_sizes[3];              // B*P (LP element count) = 8192
  cint_kernel<<<NBP, 128, 0, stream>>>(
      (const float*)d_in[0], (const float*)d_in[1], (const float*)d_in[2],
      (const float*)d_in[3], (const float*)d_in[4], (const float*)d_in[5],
      (const float*)d_in[6], (const float*)d_in[7], (const float*)d_in[8],
      (float*)d_out, NBP);
}